// Round 1
// baseline (335.372 us; speedup 1.0000x reference)
//
#include <hip/hip_runtime.h>
#include <math.h>

// SSD Detect post-processing: softmax -> decode -> per-(batch,class) top-200 + greedy NMS.
// Numerical strategy: mirror the reference's f32 op sequence exactly (explicit
// __fadd_rn/__fmul_rn/__fsub_rn/__fdiv_rn so -ffp-contract can't fuse), and use
// f64 exp rounded to f32 (~correctly rounded) wherever the reference calls exp.

constexpr int CNUM  = 21;    // classes (incl. background)
constexpr int TOPK  = 200;
constexpr int NT    = 256;   // threads per WG
constexpr int NBINS = 1024;  // histogram bins over (bits>>16)
constexpr int CAP   = 2048;  // candidate buffer (sorted by bitonic)
constexpr unsigned BIN_BASE = 0x3C23u;  // bits(0.01f)>>16

__device__ __forceinline__ float cr_expf(float x) {
  return (float)exp((double)x);  // ~correctly-rounded f32 exp
}

// ---------------- kernel 1a: softmax + transpose to [B, C-1, A] ----------------
__global__ __launch_bounds__(256) void softmax_T(
    const float* __restrict__ cls, float* __restrict__ sw, int B, int A) {
  int i = blockIdx.x * 256 + threadIdx.x;  // b*A + a
  if (i >= B * A) return;
  int b = i / A;
  int a = i - b * A;
  const float* row = cls + (size_t)i * CNUM;
  float x[CNUM];
#pragma unroll
  for (int c = 0; c < CNUM; ++c) x[c] = row[c];
  float m = x[0];
#pragma unroll
  for (int c = 1; c < CNUM; ++c) m = fmaxf(m, x[c]);
  float e[CNUM];
  float S = 0.f;
#pragma unroll
  for (int c = 0; c < CNUM; ++c) {
    e[c] = cr_expf(__fsub_rn(x[c], m));
    S = __fadd_rn(S, e[c]);
  }
#pragma unroll
  for (int c = 1; c < CNUM; ++c)
    sw[((size_t)b * (CNUM - 1) + (c - 1)) * A + a] = __fdiv_rn(e[c], S);
}

// ---------------- kernel 1b (fallback): per-row max & sum only ----------------
__global__ __launch_bounds__(256) void softmax_MS(
    const float* __restrict__ cls, float2* __restrict__ ms, int B, int A) {
  int i = blockIdx.x * 256 + threadIdx.x;
  if (i >= B * A) return;
  const float* row = cls + (size_t)i * CNUM;
  float x[CNUM];
#pragma unroll
  for (int c = 0; c < CNUM; ++c) x[c] = row[c];
  float m = x[0];
#pragma unroll
  for (int c = 1; c < CNUM; ++c) m = fmaxf(m, x[c]);
  float S = 0.f;
#pragma unroll
  for (int c = 0; c < CNUM; ++c) S = __fadd_rn(S, cr_expf(__fsub_rn(x[c], m)));
  ms[i] = make_float2(m, S);
}

__device__ __forceinline__ float score_direct(const float* __restrict__ cls,
                                              int b, int A, int a, int c) {
  const float* row = cls + ((size_t)b * A + a) * CNUM;
  float x[CNUM];
#pragma unroll
  for (int k = 0; k < CNUM; ++k) x[k] = row[k];
  float m = x[0];
#pragma unroll
  for (int k = 1; k < CNUM; ++k) m = fmaxf(m, x[k]);
  float S = 0.f, ec = 0.f;
#pragma unroll
  for (int k = 0; k < CNUM; ++k) {
    float e = cr_expf(__fsub_rn(x[k], m));
    S = __fadd_rn(S, e);
    if (k == c) ec = e;
  }
  return __fdiv_rn(ec, S);
}

// ---------------- kernel 2: per-(b,c) top-200 + NMS + write ----------------
// MODE 0: scores precomputed in sw [B, C-1, A]
// MODE 2: sw holds per-(b,a) {max, sum}; score computed from cls
// MODE 1: fully direct (no workspace)
template <int MODE>
__global__ __launch_bounds__(256) void topk_nms(
    const float* __restrict__ cls, const float* __restrict__ sw,
    const float* __restrict__ loc, const float* __restrict__ anch,
    float* __restrict__ out, int B, int A) {
  __shared__ unsigned hist[NBINS];
  __shared__ unsigned long long keys[CAP];
  __shared__ float bxv[TOPK][4];
  __shared__ float barea[TOPK];
  __shared__ float bscore[TOPK];
  __shared__ unsigned sup[TOPK][8];
  __shared__ unsigned keepm[8];
  __shared__ int s_cnt;
  __shared__ int s_T;

  const int tid = threadIdx.x;
  const int bc = blockIdx.x;
  const int b = bc / CNUM;
  const int c = bc - b * CNUM;
  float* obase = out + (size_t)bc * (TOPK * 5);
  if (c == 0) {  // background class: all zeros
    for (int i = tid; i < TOPK * 5; i += NT) obase[i] = 0.f;
    return;
  }
  const float* srow =
      (MODE == 0) ? (sw + ((size_t)b * (CNUM - 1) + (c - 1)) * A) : nullptr;
  const float2* msrow = (MODE == 2) ? ((const float2*)sw + (size_t)b * A) : nullptr;

  auto get_score = [&](int a) -> float {
    if (MODE == 0) return srow[a];
    if (MODE == 2) {
      float2 v = msrow[a];
      float xc = cls[((size_t)b * A + a) * CNUM + c];
      return __fdiv_rn(cr_expf(__fsub_rn(xc, v.x)), v.y);
    }
    return score_direct(cls, b, A, a, c);
  };

  for (int i = tid; i < NBINS; i += NT) hist[i] = 0;
  if (tid == 0) { s_cnt = 0; s_T = 0; }
  __syncthreads();

  // pass A: histogram of float bits (>>16) for scores > 0.01
  for (int a = tid; a < A; a += NT) {
    float s = get_score(a);
    if (s > 0.01f) {
      unsigned bits = __float_as_uint(s);
      int bin = (int)(bits >> 16) - (int)BIN_BASE;  // >= 0 given s > 0.01f
      bin = bin < (NBINS - 1) ? bin : (NBINS - 1);
      atomicAdd(&hist[bin], 1u);
    }
  }
  __syncthreads();

  // pass B: find threshold bin T = largest bin with suffix-count >= 200
  if (tid == 0) {
    unsigned cum = 0;
    int T = 0;
    for (int i = NBINS - 1; i >= 0; --i) {
      cum += hist[i];
      if (cum >= TOPK) { T = i; break; }
    }
    s_T = T;
  }
  __syncthreads();
  const unsigned thr_hi = (unsigned)s_T + BIN_BASE;

  // pass C: collect candidates as sortable keys (score desc, index asc)
  for (int a = tid; a < A; a += NT) {
    float s = get_score(a);
    if (s > 0.01f) {
      unsigned bits = __float_as_uint(s);
      if ((bits >> 16) >= thr_hi) {
        int pos = atomicAdd(&s_cnt, 1);
        if (pos < CAP)
          keys[pos] = ((unsigned long long)bits << 32) | (unsigned)(~(unsigned)a);
      }
    }
  }
  __syncthreads();
  int cnt = s_cnt < CAP ? s_cnt : CAP;
  for (int i = tid; i < CAP; i += NT)
    if (i >= cnt) keys[i] = 0ull;
  __syncthreads();

  // pass D: bitonic sort CAP keys, descending
  for (int size = 2; size <= CAP; size <<= 1) {
    for (int stride = size >> 1; stride > 0; stride >>= 1) {
      for (int i = tid; i < CAP; i += NT) {
        int j = i ^ stride;
        if (j > i) {
          unsigned long long ki = keys[i], kj = keys[j];
          bool desc = ((i & size) == 0);
          if (desc ? (ki < kj) : (ki > kj)) { keys[i] = kj; keys[j] = ki; }
        }
      }
      __syncthreads();
    }
  }

  const int n = cnt < TOPK ? cnt : TOPK;

  // pass E: gather + decode boxes for the top n
  if (tid < n) {
    unsigned long long k = keys[tid];
    float s = __uint_as_float((unsigned)(k >> 32));
    unsigned a = ~(unsigned)(k & 0xFFFFFFFFull);
    const float* lp = loc + ((size_t)b * A + a) * 4;
    const float* an = anch + (size_t)a * 4;
    float l0 = lp[0], l1 = lp[1], l2 = lp[2], l3 = lp[3];
    float acx = an[0], acy = an[1], aw = an[2], ah = an[3];
    float cx = __fadd_rn(acx, __fmul_rn(__fmul_rn(l0, 0.1f), aw));
    float cy = __fadd_rn(acy, __fmul_rn(__fmul_rn(l1, 0.1f), ah));
    float w  = __fmul_rn(aw, cr_expf(__fmul_rn(l2, 0.2f)));
    float h  = __fmul_rn(ah, cr_expf(__fmul_rn(l3, 0.2f)));
    float hw = __fmul_rn(w, 0.5f), hh = __fmul_rn(h, 0.5f);
    float x1 = __fsub_rn(cx, hw), y1 = __fsub_rn(cy, hh);
    float x2 = __fadd_rn(cx, hw), y2 = __fadd_rn(cy, hh);
    bxv[tid][0] = x1; bxv[tid][1] = y1; bxv[tid][2] = x2; bxv[tid][3] = y2;
    barea[tid] = __fmul_rn(fmaxf(__fsub_rn(x2, x1), 0.f),
                           fmaxf(__fsub_rn(y2, y1), 0.f));
    bscore[tid] = s;
  }
  for (int i = tid; i < TOPK * 8; i += NT) ((unsigned*)sup)[i] = 0u;
  __syncthreads();

  // pass F: parallel pairwise IoU -> suppression bitmask (j > i only)
  for (int idx = tid; idx < TOPK * TOPK; idx += NT) {
    int i = idx / TOPK;
    int j = idx - i * TOPK;
    if (j > i && j < n && i < n) {
      float ltx = fmaxf(bxv[i][0], bxv[j][0]);
      float lty = fmaxf(bxv[i][1], bxv[j][1]);
      float rbx = fminf(bxv[i][2], bxv[j][2]);
      float rby = fminf(bxv[i][3], bxv[j][3]);
      float iw = fmaxf(__fsub_rn(rbx, ltx), 0.f);
      float ih = fmaxf(__fsub_rn(rby, lty), 0.f);
      float inter = __fmul_rn(iw, ih);
      float denom = __fadd_rn(__fsub_rn(__fadd_rn(barea[i], barea[j]), inter), 1e-9f);
      float iou = __fdiv_rn(inter, denom);
      if (iou > 0.45f) atomicOr(&sup[i][j >> 5], 1u << (j & 31));
    }
  }
  __syncthreads();

  // pass G: serial greedy resolve on one thread (800 LDS word-ops, no barriers)
  if (tid == 0) {
    unsigned km[8];
#pragma unroll
    for (int w = 0; w < 8; ++w) {
      int lo = w * 32;
      unsigned m2;
      if (n >= lo + 32) m2 = 0xFFFFFFFFu;
      else if (n <= lo) m2 = 0u;
      else m2 = (1u << (n - lo)) - 1u;
      km[w] = m2;
    }
    for (int i = 0; i < n; ++i) {
      if ((km[i >> 5] >> (i & 31)) & 1u) {
#pragma unroll
        for (int w = 0; w < 8; ++w) km[w] &= ~sup[i][w];
      }
    }
#pragma unroll
    for (int w = 0; w < 8; ++w) keepm[w] = km[w];
  }
  __syncthreads();

  // pass H: write 200 rows of (score, x1, y1, x2, y2)
  if (tid < TOPK) {
    float s = 0.f, o0 = 0.f, o1 = 0.f, o2 = 0.f, o3 = 0.f;
    if (tid < n && ((keepm[tid >> 5] >> (tid & 31)) & 1u)) {
      s = bscore[tid];
      o0 = bxv[tid][0]; o1 = bxv[tid][1]; o2 = bxv[tid][2]; o3 = bxv[tid][3];
    }
    obase[tid * 5 + 0] = s;
    obase[tid * 5 + 1] = o0;
    obase[tid * 5 + 2] = o1;
    obase[tid * 5 + 3] = o2;
    obase[tid * 5 + 4] = o3;
  }
}

extern "C" void kernel_launch(void* const* d_in, const int* in_sizes, int n_in,
                              void* d_out, int out_size, void* d_ws, size_t ws_size,
                              hipStream_t stream) {
  const float* cls  = (const float*)d_in[0];
  const float* loc  = (const float*)d_in[1];
  const float* anch = (const float*)d_in[2];
  float* out = (float*)d_out;

  const int A = in_sizes[2] / 4;
  const int B = in_sizes[1] / (4 * A);
  // CNUM is hard-coded 21 (in_sizes[0]/(A*B)); reference fixes C=21.

  const int tot = B * A;
  const size_t need_full = (size_t)B * (CNUM - 1) * A * sizeof(float);
  const size_t need_ms   = (size_t)tot * sizeof(float2);

  if (ws_size >= need_full) {
    float* sw = (float*)d_ws;
    softmax_T<<<(tot + 255) / 256, 256, 0, stream>>>(cls, sw, B, A);
    topk_nms<0><<<B * CNUM, NT, 0, stream>>>(cls, sw, loc, anch, out, B, A);
  } else if (ws_size >= need_ms) {
    float2* ms = (float2*)d_ws;
    softmax_MS<<<(tot + 255) / 256, 256, 0, stream>>>(cls, ms, B, A);
    topk_nms<2><<<B * CNUM, NT, 0, stream>>>(cls, (const float*)ms, loc, anch, out, B, A);
  } else {
    topk_nms<1><<<B * CNUM, NT, 0, stream>>>(cls, nullptr, loc, anch, out, B, A);
  }
}

// Round 4
// 328.033 us; speedup vs baseline: 1.0224x; 1.0224x over previous
//
#include <hip/hip_runtime.h>
#include <math.h>

// SSD Detect post-processing, split-pipeline version:
//   K1 softmax_T4 : softmax + transpose to [B,20,A], 4 anchors/thread, float4 IO
//   K2 hist_k     : per-(b,c) score histogram, 8 slice-blocks each, LDS + atomics
//   K3 thr_k      : exact top-200 threshold bin per (b,c)
//   K4 collect_k  : compact candidate keys >= threshold into global buffers
//   K5 nms_k      : sort next_pow2(cnt) + decode + IoU + greedy NMS + write
// Numerics mirror the reference f32 op sequence (explicit __f*_rn, f64 exp).

constexpr int CNUM  = 21;
constexpr int CC    = 20;      // foreground classes
constexpr int TOPK  = 200;
constexpr int NT    = 256;
constexpr int NBINS = 1024;
constexpr int CAP   = 2048;
constexpr int SLICES = 8;
constexpr unsigned BIN_BASE = 0x3C23u;  // bits(0.01f)>>16

__device__ __forceinline__ float cr_expf(float x) {
  return (float)exp((double)x);  // ~correctly-rounded f32 exp
}

// ---------------- K1: softmax + transpose, 4 rows/thread ----------------
__global__ __launch_bounds__(256) void softmax_T4(
    const float* __restrict__ cls, float* __restrict__ sw, int B, int A) {
  const long long r0 = ((long long)blockIdx.x * 256 + threadIdx.x) * 4;
  const long long BA = (long long)B * A;
  if (r0 >= BA) return;

  if (r0 + 3 < BA && (A & 3) == 0) {
    // 4 rows, same image (A%4==0 and r0%4==0 => no image straddle)
    const int b = (int)(r0 / A);
    const int a0 = (int)(r0 - (long long)b * A);
    float xf[84];
    const float4* p = (const float4*)(cls + r0 * CNUM);
#pragma unroll
    for (int k = 0; k < 21; ++k) {  // 84 floats = 21 aligned float4
      float4 q = p[k];
      xf[4 * k + 0] = q.x; xf[4 * k + 1] = q.y;
      xf[4 * k + 2] = q.z; xf[4 * k + 3] = q.w;
    }
    float S[4];
#pragma unroll
    for (int r = 0; r < 4; ++r) {
      const int base = 21 * r;
      float m = xf[base];
#pragma unroll
      for (int c = 1; c < CNUM; ++c) m = fmaxf(m, xf[base + c]);
      float s = 0.f;
#pragma unroll
      for (int c = 0; c < CNUM; ++c) {
        float e = cr_expf(__fsub_rn(xf[base + c], m));
        xf[base + c] = e;  // overwrite x with e
        s = __fadd_rn(s, e);
      }
      S[r] = s;
    }
#pragma unroll
    for (int c = 1; c < CNUM; ++c) {
      float4 w;
      w.x = __fdiv_rn(xf[0 * 21 + c], S[0]);
      w.y = __fdiv_rn(xf[1 * 21 + c], S[1]);
      w.z = __fdiv_rn(xf[2 * 21 + c], S[2]);
      w.w = __fdiv_rn(xf[3 * 21 + c], S[3]);
      *(float4*)(sw + ((size_t)b * CC + (c - 1)) * A + a0) = w;
    }
  } else {
    // generic scalar tail
    for (long long r = r0; r < BA && r < r0 + 4; ++r) {
      const int b = (int)(r / A);
      const int a = (int)(r - (long long)b * A);
      const float* row = cls + r * CNUM;
      float x[CNUM];
#pragma unroll
      for (int c = 0; c < CNUM; ++c) x[c] = row[c];
      float m = x[0];
#pragma unroll
      for (int c = 1; c < CNUM; ++c) m = fmaxf(m, x[c]);
      float e[CNUM], s = 0.f;
#pragma unroll
      for (int c = 0; c < CNUM; ++c) {
        e[c] = cr_expf(__fsub_rn(x[c], m));
        s = __fadd_rn(s, e[c]);
      }
#pragma unroll
      for (int c = 1; c < CNUM; ++c)
        sw[((size_t)b * CC + (c - 1)) * A + a] = __fdiv_rn(e[c], s);
    }
  }
}

// ---------------- K2: sliced histogram ----------------
__global__ __launch_bounds__(256) void hist_k(
    const float* __restrict__ sw, unsigned* __restrict__ ghist, int A) {
  __shared__ unsigned hist[NBINS];
  const int bc = blockIdx.x / SLICES;
  const int sl = blockIdx.x % SLICES;
  const int tid = threadIdx.x;
  for (int i = tid; i < NBINS; i += NT) hist[i] = 0;
  __syncthreads();

  const float* srow = sw + (size_t)bc * A;
  const int n4 = A >> 2;
  const int per4 = (n4 + SLICES - 1) / SLICES;
  const int s4 = sl * per4, e4 = min(n4, s4 + per4);
  const float4* srow4 = (const float4*)srow;
  for (int i = s4 + tid; i < e4; i += NT) {
    float4 v = srow4[i];
    float vs[4] = {v.x, v.y, v.z, v.w};
#pragma unroll
    for (int j = 0; j < 4; ++j) {
      float s = vs[j];
      if (s > 0.01f) {
        unsigned bits = __float_as_uint(s);
        int bin = (int)(bits >> 16) - (int)BIN_BASE;
        bin = bin < (NBINS - 1) ? bin : (NBINS - 1);
        atomicAdd(&hist[bin], 1u);
      }
    }
  }
  // scalar tail (A%4): only slice 0 handles it
  if (sl == 0)
    for (int a = (n4 << 2) + tid; a < A; a += NT) {
      float s = srow[a];
      if (s > 0.01f) {
        unsigned bits = __float_as_uint(s);
        int bin = (int)(bits >> 16) - (int)BIN_BASE;
        bin = bin < (NBINS - 1) ? bin : (NBINS - 1);
        atomicAdd(&hist[bin], 1u);
      }
    }
  __syncthreads();
  for (int i = tid; i < NBINS; i += NT) {
    unsigned h = hist[i];
    if (h) atomicAdd(&ghist[(size_t)bc * NBINS + i], h);
  }
}

// ---------------- K3: threshold bin per (b,c) ----------------
__global__ __launch_bounds__(64) void thr_k(
    const unsigned* __restrict__ ghist, unsigned* __restrict__ thr) {
  __shared__ unsigned binsh[NBINS];
  __shared__ unsigned ps[64];
  const int bc = blockIdx.x;
  const int lane = threadIdx.x;
  unsigned sum = 0;
#pragma unroll
  for (int k = 0; k < NBINS / 64; ++k) {
    int b = lane * (NBINS / 64) + k;
    unsigned h = ghist[(size_t)bc * NBINS + b];
    binsh[b] = h;
    sum += h;
  }
  ps[lane] = sum;
  __syncthreads();
  if (lane == 0) {
    unsigned cum = 0;
    int T = 0;
    for (int l = 63; l >= 0; --l) {
      if (cum + ps[l] >= (unsigned)TOPK) {
        for (int b = l * (NBINS / 64) + (NBINS / 64) - 1; b >= l * (NBINS / 64); --b) {
          cum += binsh[b];
          if (cum >= (unsigned)TOPK) { T = b; break; }
        }
        break;
      }
      cum += ps[l];
    }
    thr[bc] = (unsigned)T + BIN_BASE;
  }
}

// ---------------- K4: collect candidates ----------------
__global__ __launch_bounds__(256) void collect_k(
    const float* __restrict__ sw, const unsigned* __restrict__ thr,
    unsigned long long* __restrict__ cand, unsigned* __restrict__ cnt, int A) {
  const int bc = blockIdx.x / SLICES;
  const int sl = blockIdx.x % SLICES;
  const int tid = threadIdx.x;
  const unsigned thr_hi = thr[bc];
  const float* srow = sw + (size_t)bc * A;
  unsigned long long* cbase = cand + (size_t)bc * CAP;

  const int n4 = A >> 2;
  const int per4 = (n4 + SLICES - 1) / SLICES;
  const int s4 = sl * per4, e4 = min(n4, s4 + per4);
  const float4* srow4 = (const float4*)srow;
  for (int i = s4 + tid; i < e4; i += NT) {
    float4 v = srow4[i];
    float vs[4] = {v.x, v.y, v.z, v.w};
#pragma unroll
    for (int j = 0; j < 4; ++j) {
      float s = vs[j];
      if (s > 0.01f) {
        unsigned bits = __float_as_uint(s);
        if ((bits >> 16) >= thr_hi) {
          unsigned a = (unsigned)(i * 4 + j);
          unsigned pos = atomicAdd(&cnt[bc], 1u);
          if (pos < CAP)
            cbase[pos] = ((unsigned long long)bits << 32) | (unsigned)(~a);
        }
      }
    }
  }
  if (sl == 0)
    for (int a = (n4 << 2) + tid; a < A; a += NT) {
      float s = srow[a];
      if (s > 0.01f) {
        unsigned bits = __float_as_uint(s);
        if ((bits >> 16) >= thr_hi) {
          unsigned pos = atomicAdd(&cnt[bc], 1u);
          if (pos < CAP)
            cbase[pos] = ((unsigned long long)bits << 32) | (unsigned)(~(unsigned)a);
        }
      }
    }
}

// ---------------- K5: sort + decode + NMS + write ----------------
__global__ __launch_bounds__(256) void nms_k(
    const unsigned long long* __restrict__ cand, const unsigned* __restrict__ cnt,
    const float* __restrict__ loc, const float* __restrict__ anch,
    float* __restrict__ out, int B, int A) {
  __shared__ unsigned long long keys[CAP];
  __shared__ float bxv[TOPK][4];
  __shared__ float barea[TOPK];
  __shared__ float bscore[TOPK];
  __shared__ unsigned sup[TOPK][8];
  __shared__ unsigned keepm[8];

  const int tid = threadIdx.x;
  const int bc = blockIdx.x;       // b*21 + c
  const int b = bc / CNUM;
  const int c = bc - b * CNUM;
  float* obase = out + (size_t)bc * (TOPK * 5);
  if (c == 0) {
    for (int i = tid; i < TOPK * 5; i += NT) obase[i] = 0.f;
    return;
  }
  const int bc20 = b * CC + (c - 1);
  int rawcnt = (int)cnt[bc20];
  const int n_cand = rawcnt < CAP ? rawcnt : CAP;

  int P2 = 256;
  while (P2 < n_cand) P2 <<= 1;   // n_cand <= CAP = 2048

  const unsigned long long* cbase = cand + (size_t)bc20 * CAP;
  for (int i = tid; i < P2; i += NT)
    keys[i] = (i < n_cand) ? cbase[i] : 0ull;
  __syncthreads();

  for (int size = 2; size <= P2; size <<= 1) {
    for (int stride = size >> 1; stride > 0; stride >>= 1) {
      for (int i = tid; i < P2; i += NT) {
        int j = i ^ stride;
        if (j > i) {
          unsigned long long ki = keys[i], kj = keys[j];
          bool desc = ((i & size) == 0);
          if (desc ? (ki < kj) : (ki > kj)) { keys[i] = kj; keys[j] = ki; }
        }
      }
      __syncthreads();
    }
  }

  const int n = n_cand < TOPK ? n_cand : TOPK;

  if (tid < n) {
    unsigned long long k = keys[tid];
    float s = __uint_as_float((unsigned)(k >> 32));
    unsigned a = ~(unsigned)(k & 0xFFFFFFFFull);
    const float* lp = loc + ((size_t)b * A + a) * 4;
    const float* an = anch + (size_t)a * 4;
    float l0 = lp[0], l1 = lp[1], l2 = lp[2], l3 = lp[3];
    float acx = an[0], acy = an[1], aw = an[2], ah = an[3];
    float cx = __fadd_rn(acx, __fmul_rn(__fmul_rn(l0, 0.1f), aw));
    float cy = __fadd_rn(acy, __fmul_rn(__fmul_rn(l1, 0.1f), ah));
    float w  = __fmul_rn(aw, cr_expf(__fmul_rn(l2, 0.2f)));
    float h  = __fmul_rn(ah, cr_expf(__fmul_rn(l3, 0.2f)));
    float hw = __fmul_rn(w, 0.5f), hh = __fmul_rn(h, 0.5f);
    float x1 = __fsub_rn(cx, hw), y1 = __fsub_rn(cy, hh);
    float x2 = __fadd_rn(cx, hw), y2 = __fadd_rn(cy, hh);
    bxv[tid][0] = x1; bxv[tid][1] = y1; bxv[tid][2] = x2; bxv[tid][3] = y2;
    barea[tid] = __fmul_rn(fmaxf(__fsub_rn(x2, x1), 0.f),
                           fmaxf(__fsub_rn(y2, y1), 0.f));
    bscore[tid] = s;
  }
  for (int i = tid; i < TOPK * 8; i += NT) ((unsigned*)sup)[i] = 0u;
  __syncthreads();

  for (int idx = tid; idx < TOPK * TOPK; idx += NT) {
    int i = idx / TOPK;
    int j = idx - i * TOPK;
    if (j > i && j < n && i < n) {
      float ltx = fmaxf(bxv[i][0], bxv[j][0]);
      float lty = fmaxf(bxv[i][1], bxv[j][1]);
      float rbx = fminf(bxv[i][2], bxv[j][2]);
      float rby = fminf(bxv[i][3], bxv[j][3]);
      float iw = fmaxf(__fsub_rn(rbx, ltx), 0.f);
      float ih = fmaxf(__fsub_rn(rby, lty), 0.f);
      float inter = __fmul_rn(iw, ih);
      float denom = __fadd_rn(__fsub_rn(__fadd_rn(barea[i], barea[j]), inter), 1e-9f);
      float iou = __fdiv_rn(inter, denom);
      if (iou > 0.45f) atomicOr(&sup[i][j >> 5], 1u << (j & 31));
    }
  }
  __syncthreads();

  if (tid == 0) {
    unsigned km[8];
#pragma unroll
    for (int w = 0; w < 8; ++w) {
      int lo = w * 32;
      unsigned m2;
      if (n >= lo + 32) m2 = 0xFFFFFFFFu;
      else if (n <= lo) m2 = 0u;
      else m2 = (1u << (n - lo)) - 1u;
      km[w] = m2;
    }
    for (int i = 0; i < n; ++i) {
      if ((km[i >> 5] >> (i & 31)) & 1u) {
#pragma unroll
        for (int w = 0; w < 8; ++w) km[w] &= ~sup[i][w];
      }
    }
#pragma unroll
    for (int w = 0; w < 8; ++w) keepm[w] = km[w];
  }
  __syncthreads();

  if (tid < TOPK) {
    float s = 0.f, o0 = 0.f, o1 = 0.f, o2 = 0.f, o3 = 0.f;
    if (tid < n && ((keepm[tid >> 5] >> (tid & 31)) & 1u)) {
      s = bscore[tid];
      o0 = bxv[tid][0]; o1 = bxv[tid][1]; o2 = bxv[tid][2]; o3 = bxv[tid][3];
    }
    obase[tid * 5 + 0] = s;
    obase[tid * 5 + 1] = o0;
    obase[tid * 5 + 2] = o1;
    obase[tid * 5 + 3] = o2;
    obase[tid * 5 + 4] = o3;
  }
}

// ================= legacy fallback (R1 path, small workspace) =================
__global__ __launch_bounds__(256) void softmax_MS(
    const float* __restrict__ cls, float2* __restrict__ ms, int B, int A) {
  int i = blockIdx.x * 256 + threadIdx.x;
  if (i >= B * A) return;
  const float* row = cls + (size_t)i * CNUM;
  float x[CNUM];
#pragma unroll
  for (int c = 0; c < CNUM; ++c) x[c] = row[c];
  float m = x[0];
#pragma unroll
  for (int c = 1; c < CNUM; ++c) m = fmaxf(m, x[c]);
  float S = 0.f;
#pragma unroll
  for (int c = 0; c < CNUM; ++c) S = __fadd_rn(S, cr_expf(__fsub_rn(x[c], m)));
  ms[i] = make_float2(m, S);
}

__device__ __forceinline__ float score_direct(const float* __restrict__ cls,
                                              int b, int A, int a, int c) {
  const float* row = cls + ((size_t)b * A + a) * CNUM;
  float x[CNUM];
#pragma unroll
  for (int k = 0; k < CNUM; ++k) x[k] = row[k];
  float m = x[0];
#pragma unroll
  for (int k = 1; k < CNUM; ++k) m = fmaxf(m, x[k]);
  float S = 0.f, ec = 0.f;
#pragma unroll
  for (int k = 0; k < CNUM; ++k) {
    float e = cr_expf(__fsub_rn(x[k], m));
    S = __fadd_rn(S, e);
    if (k == c) ec = e;
  }
  return __fdiv_rn(ec, S);
}

template <int MODE>
__global__ __launch_bounds__(256) void topk_nms(
    const float* __restrict__ cls, const float* __restrict__ sw,
    const float* __restrict__ loc, const float* __restrict__ anch,
    float* __restrict__ out, int B, int A) {
  __shared__ unsigned hist[NBINS];
  __shared__ unsigned long long keys[CAP];
  __shared__ float bxv[TOPK][4];
  __shared__ float barea[TOPK];
  __shared__ float bscore[TOPK];
  __shared__ unsigned sup[TOPK][8];
  __shared__ unsigned keepm[8];
  __shared__ int s_cnt;
  __shared__ int s_T;

  const int tid = threadIdx.x;
  const int bc = blockIdx.x;
  const int b = bc / CNUM;
  const int c = bc - b * CNUM;
  float* obase = out + (size_t)bc * (TOPK * 5);
  if (c == 0) {
    for (int i = tid; i < TOPK * 5; i += NT) obase[i] = 0.f;
    return;
  }
  const float* srow =
      (MODE == 0) ? (sw + ((size_t)b * CC + (c - 1)) * A) : nullptr;
  const float2* msrow = (MODE == 2) ? ((const float2*)sw + (size_t)b * A) : nullptr;

  auto get_score = [&](int a) -> float {
    if (MODE == 0) return srow[a];
    if (MODE == 2) {
      float2 v = msrow[a];
      float xc = cls[((size_t)b * A + a) * CNUM + c];
      return __fdiv_rn(cr_expf(__fsub_rn(xc, v.x)), v.y);
    }
    return score_direct(cls, b, A, a, c);
  };

  for (int i = tid; i < NBINS; i += NT) hist[i] = 0;
  if (tid == 0) { s_cnt = 0; s_T = 0; }
  __syncthreads();

  for (int a = tid; a < A; a += NT) {
    float s = get_score(a);
    if (s > 0.01f) {
      unsigned bits = __float_as_uint(s);
      int bin = (int)(bits >> 16) - (int)BIN_BASE;
      bin = bin < (NBINS - 1) ? bin : (NBINS - 1);
      atomicAdd(&hist[bin], 1u);
    }
  }
  __syncthreads();

  if (tid == 0) {
    unsigned cum = 0;
    int T = 0;
    for (int i = NBINS - 1; i >= 0; --i) {
      cum += hist[i];
      if (cum >= TOPK) { T = i; break; }
    }
    s_T = T;
  }
  __syncthreads();
  const unsigned thr_hi = (unsigned)s_T + BIN_BASE;

  for (int a = tid; a < A; a += NT) {
    float s = get_score(a);
    if (s > 0.01f) {
      unsigned bits = __float_as_uint(s);
      if ((bits >> 16) >= thr_hi) {
        int pos = atomicAdd(&s_cnt, 1);
        if (pos < CAP)
          keys[pos] = ((unsigned long long)bits << 32) | (unsigned)(~(unsigned)a);
      }
    }
  }
  __syncthreads();
  int cnt = s_cnt < CAP ? s_cnt : CAP;
  for (int i = tid; i < CAP; i += NT)
    if (i >= cnt) keys[i] = 0ull;
  __syncthreads();

  for (int size = 2; size <= CAP; size <<= 1) {
    for (int stride = size >> 1; stride > 0; stride >>= 1) {
      for (int i = tid; i < CAP; i += NT) {
        int j = i ^ stride;
        if (j > i) {
          unsigned long long ki = keys[i], kj = keys[j];
          bool desc = ((i & size) == 0);
          if (desc ? (ki < kj) : (ki > kj)) { keys[i] = kj; keys[j] = ki; }
        }
      }
      __syncthreads();
    }
  }

  const int n = cnt < TOPK ? cnt : TOPK;

  if (tid < n) {
    unsigned long long k = keys[tid];
    float s = __uint_as_float((unsigned)(k >> 32));
    unsigned a = ~(unsigned)(k & 0xFFFFFFFFull);
    const float* lp = loc + ((size_t)b * A + a) * 4;
    const float* an = anch + (size_t)a * 4;
    float l0 = lp[0], l1 = lp[1], l2 = lp[2], l3 = lp[3];
    float acx = an[0], acy = an[1], aw = an[2], ah = an[3];
    float cx = __fadd_rn(acx, __fmul_rn(__fmul_rn(l0, 0.1f), aw));
    float cy = __fadd_rn(acy, __fmul_rn(__fmul_rn(l1, 0.1f), ah));
    float w  = __fmul_rn(aw, cr_expf(__fmul_rn(l2, 0.2f)));
    float h  = __fmul_rn(ah, cr_expf(__fmul_rn(l3, 0.2f)));
    float hw = __fmul_rn(w, 0.5f), hh = __fmul_rn(h, 0.5f);
    float x1 = __fsub_rn(cx, hw), y1 = __fsub_rn(cy, hh);
    float x2 = __fadd_rn(cx, hw), y2 = __fadd_rn(cy, hh);
    bxv[tid][0] = x1; bxv[tid][1] = y1; bxv[tid][2] = x2; bxv[tid][3] = y2;
    barea[tid] = __fmul_rn(fmaxf(__fsub_rn(x2, x1), 0.f),
                           fmaxf(__fsub_rn(y2, y1), 0.f));
    bscore[tid] = s;
  }
  for (int i = tid; i < TOPK * 8; i += NT) ((unsigned*)sup)[i] = 0u;
  __syncthreads();

  for (int idx = tid; idx < TOPK * TOPK; idx += NT) {
    int i = idx / TOPK;
    int j = idx - i * TOPK;
    if (j > i && j < n && i < n) {
      float ltx = fmaxf(bxv[i][0], bxv[j][0]);
      float lty = fmaxf(bxv[i][1], bxv[j][1]);
      float rbx = fminf(bxv[i][2], bxv[j][2]);
      float rby = fminf(bxv[i][3], bxv[j][3]);
      float iw = fmaxf(__fsub_rn(rbx, ltx), 0.f);
      float ih = fmaxf(__fsub_rn(rby, lty), 0.f);
      float inter = __fmul_rn(iw, ih);
      float denom = __fadd_rn(__fsub_rn(__fadd_rn(barea[i], barea[j]), inter), 1e-9f);
      float iou = __fdiv_rn(inter, denom);
      if (iou > 0.45f) atomicOr(&sup[i][j >> 5], 1u << (j & 31));
    }
  }
  __syncthreads();

  if (tid == 0) {
    unsigned km[8];
#pragma unroll
    for (int w = 0; w < 8; ++w) {
      int lo = w * 32;
      unsigned m2;
      if (n >= lo + 32) m2 = 0xFFFFFFFFu;
      else if (n <= lo) m2 = 0u;
      else m2 = (1u << (n - lo)) - 1u;
      km[w] = m2;
    }
    for (int i = 0; i < n; ++i) {
      if ((km[i >> 5] >> (i & 31)) & 1u) {
#pragma unroll
        for (int w = 0; w < 8; ++w) km[w] &= ~sup[i][w];
      }
    }
#pragma unroll
    for (int w = 0; w < 8; ++w) keepm[w] = km[w];
  }
  __syncthreads();

  if (tid < TOPK) {
    float s = 0.f, o0 = 0.f, o1 = 0.f, o2 = 0.f, o3 = 0.f;
    if (tid < n && ((keepm[tid >> 5] >> (tid & 31)) & 1u)) {
      s = bscore[tid];
      o0 = bxv[tid][0]; o1 = bxv[tid][1]; o2 = bxv[tid][2]; o3 = bxv[tid][3];
    }
    obase[tid * 5 + 0] = s;
    obase[tid * 5 + 1] = o0;
    obase[tid * 5 + 2] = o1;
    obase[tid * 5 + 3] = o2;
    obase[tid * 5 + 4] = o3;
  }
}

extern "C" void kernel_launch(void* const* d_in, const int* in_sizes, int n_in,
                              void* d_out, int out_size, void* d_ws, size_t ws_size,
                              hipStream_t stream) {
  const float* cls  = (const float*)d_in[0];
  const float* loc  = (const float*)d_in[1];
  const float* anch = (const float*)d_in[2];
  float* out = (float*)d_out;

  const int A = in_sizes[2] / 4;
  const int B = in_sizes[1] / (4 * A);
  const long long BA = (long long)B * A;
  const int NBC = B * CC;  // 640 foreground (b,c) pairs

  // workspace layout (256-aligned pieces)
  auto al = [](size_t x) { return (x + 255) & ~(size_t)255; };
  const size_t sz_sw   = al((size_t)NBC * A * sizeof(float));
  const size_t sz_cand = al((size_t)NBC * CAP * sizeof(unsigned long long));
  const size_t sz_hist = al((size_t)NBC * NBINS * sizeof(unsigned));
  const size_t sz_cnt  = al((size_t)NBC * sizeof(unsigned));
  const size_t sz_thr  = al((size_t)NBC * sizeof(unsigned));
  const size_t need_new = sz_sw + sz_cand + sz_hist + sz_cnt + sz_thr;

  if (ws_size >= need_new) {
    char* w = (char*)d_ws;
    float* sw = (float*)w;
    unsigned long long* cand = (unsigned long long*)(w + sz_sw);
    unsigned* ghist = (unsigned*)(w + sz_sw + sz_cand);
    unsigned* cnt = (unsigned*)(w + sz_sw + sz_cand + sz_hist);
    unsigned* thr = (unsigned*)(w + sz_sw + sz_cand + sz_hist + sz_cnt);

    // zero hist + cnt (contiguous region)
    hipMemsetAsync(ghist, 0, sz_hist + sz_cnt, stream);

    const int k1_grid = (int)((BA / 4 + 255) / 256) + 1;
    softmax_T4<<<k1_grid, 256, 0, stream>>>(cls, sw, B, A);
    hist_k<<<NBC * SLICES, NT, 0, stream>>>(sw, ghist, A);
    thr_k<<<NBC, 64, 0, stream>>>(ghist, thr);
    collect_k<<<NBC * SLICES, NT, 0, stream>>>(sw, thr, cand, cnt, A);
    nms_k<<<B * CNUM, NT, 0, stream>>>(cand, cnt, loc, anch, out, B, A);
    return;
  }

  // legacy fallbacks
  const size_t need_full = (size_t)NBC * A * sizeof(float);
  const size_t need_ms   = (size_t)BA * sizeof(float2);
  const int tot = (int)BA;
  if (ws_size >= need_full) {
    float* sw = (float*)d_ws;
    const int k1_grid = (int)((BA / 4 + 255) / 256) + 1;
    softmax_T4<<<k1_grid, 256, 0, stream>>>(cls, sw, B, A);
    topk_nms<0><<<B * CNUM, NT, 0, stream>>>(cls, sw, loc, anch, out, B, A);
  } else if (ws_size >= need_ms) {
    float2* ms = (float2*)d_ws;
    softmax_MS<<<(tot + 255) / 256, 256, 0, stream>>>(cls, ms, B, A);
    topk_nms<2><<<B * CNUM, NT, 0, stream>>>(cls, (const float*)ms, loc, anch, out, B, A);
  } else {
    topk_nms<1><<<B * CNUM, NT, 0, stream>>>(cls, nullptr, loc, anch, out, B, A);
  }
}

// Round 9
// 232.654 us; speedup vs baseline: 1.4415x; 1.4100x over previous
//
#include <hip/hip_runtime.h>
#include <math.h>

// SSD Detect post-processing, split-pipeline version (R5):
//   K1 softmax_T4 : softmax + transpose to [B,20,A], 4 anchors/thread, float4 IO
//   K2 hist_k     : per-(b,c) score histogram, 8 slice-blocks each, LDS + atomics
//   K3 thr_k      : exact top-200 threshold bin per (b,c)
//   K4 collect_k  : compact candidates into PER-SLICE segments via LDS counter
//                   (no global atomics-with-return — R4 showed those serialize
//                    at ~0.5us/op on 640 hot addresses = 113us)
//   K5 nms_k      : gather segments + sort next_pow2(cnt) + decode + IoU + NMS
// Numerics mirror the reference f32 op sequence (explicit __f*_rn, f64 exp).

constexpr int CNUM  = 21;
constexpr int CC    = 20;      // foreground classes
constexpr int TOPK  = 200;
constexpr int NT    = 256;
constexpr int NBINS = 1024;
constexpr int SLICES = 8;
constexpr int SEGCAP = 256;            // per-slice candidate capacity
constexpr int CAP   = SLICES * SEGCAP; // 2048, sort buffer size
constexpr unsigned BIN_BASE = 0x3C23u;  // bits(0.01f)>>16

__device__ __forceinline__ float cr_expf(float x) {
  return (float)exp((double)x);  // ~correctly-rounded f32 exp
}

// ---------------- K1: softmax + transpose, 4 rows/thread ----------------
__global__ __launch_bounds__(256) void softmax_T4(
    const float* __restrict__ cls, float* __restrict__ sw, int B, int A) {
  const long long r0 = ((long long)blockIdx.x * 256 + threadIdx.x) * 4;
  const long long BA = (long long)B * A;
  if (r0 >= BA) return;

  if (r0 + 3 < BA && (A & 3) == 0) {
    // 4 rows, same image (A%4==0 and r0%4==0 => no image straddle)
    const int b = (int)(r0 / A);
    const int a0 = (int)(r0 - (long long)b * A);
    float xf[84];
    const float4* p = (const float4*)(cls + r0 * CNUM);
#pragma unroll
    for (int k = 0; k < 21; ++k) {  // 84 floats = 21 aligned float4
      float4 q = p[k];
      xf[4 * k + 0] = q.x; xf[4 * k + 1] = q.y;
      xf[4 * k + 2] = q.z; xf[4 * k + 3] = q.w;
    }
    float S[4];
#pragma unroll
    for (int r = 0; r < 4; ++r) {
      const int base = 21 * r;
      float m = xf[base];
#pragma unroll
      for (int c = 1; c < CNUM; ++c) m = fmaxf(m, xf[base + c]);
      float s = 0.f;
#pragma unroll
      for (int c = 0; c < CNUM; ++c) {
        float e = cr_expf(__fsub_rn(xf[base + c], m));
        xf[base + c] = e;  // overwrite x with e
        s = __fadd_rn(s, e);
      }
      S[r] = s;
    }
#pragma unroll
    for (int c = 1; c < CNUM; ++c) {
      float4 w;
      w.x = __fdiv_rn(xf[0 * 21 + c], S[0]);
      w.y = __fdiv_rn(xf[1 * 21 + c], S[1]);
      w.z = __fdiv_rn(xf[2 * 21 + c], S[2]);
      w.w = __fdiv_rn(xf[3 * 21 + c], S[3]);
      *(float4*)(sw + ((size_t)b * CC + (c - 1)) * A + a0) = w;
    }
  } else {
    // generic scalar tail
    for (long long r = r0; r < BA && r < r0 + 4; ++r) {
      const int b = (int)(r / A);
      const int a = (int)(r - (long long)b * A);
      const float* row = cls + r * CNUM;
      float x[CNUM];
#pragma unroll
      for (int c = 0; c < CNUM; ++c) x[c] = row[c];
      float m = x[0];
#pragma unroll
      for (int c = 1; c < CNUM; ++c) m = fmaxf(m, x[c]);
      float e[CNUM], s = 0.f;
#pragma unroll
      for (int c = 0; c < CNUM; ++c) {
        e[c] = cr_expf(__fsub_rn(x[c], m));
        s = __fadd_rn(s, e[c]);
      }
#pragma unroll
      for (int c = 1; c < CNUM; ++c)
        sw[((size_t)b * CC + (c - 1)) * A + a] = __fdiv_rn(e[c], s);
    }
  }
}

// ---------------- K2: sliced histogram ----------------
__global__ __launch_bounds__(256) void hist_k(
    const float* __restrict__ sw, unsigned* __restrict__ ghist, int A) {
  __shared__ unsigned hist[NBINS];
  const int bc = blockIdx.x / SLICES;
  const int sl = blockIdx.x % SLICES;
  const int tid = threadIdx.x;
  for (int i = tid; i < NBINS; i += NT) hist[i] = 0;
  __syncthreads();

  const float* srow = sw + (size_t)bc * A;
  const int n4 = A >> 2;
  const int per4 = (n4 + SLICES - 1) / SLICES;
  const int s4 = sl * per4, e4 = min(n4, s4 + per4);
  const float4* srow4 = (const float4*)srow;
  for (int i = s4 + tid; i < e4; i += NT) {
    float4 v = srow4[i];
    float vs[4] = {v.x, v.y, v.z, v.w};
#pragma unroll
    for (int j = 0; j < 4; ++j) {
      float s = vs[j];
      if (s > 0.01f) {
        unsigned bits = __float_as_uint(s);
        int bin = (int)(bits >> 16) - (int)BIN_BASE;
        bin = bin < (NBINS - 1) ? bin : (NBINS - 1);
        atomicAdd(&hist[bin], 1u);
      }
    }
  }
  // scalar tail (A%4): only slice 0 handles it
  if (sl == 0)
    for (int a = (n4 << 2) + tid; a < A; a += NT) {
      float s = srow[a];
      if (s > 0.01f) {
        unsigned bits = __float_as_uint(s);
        int bin = (int)(bits >> 16) - (int)BIN_BASE;
        bin = bin < (NBINS - 1) ? bin : (NBINS - 1);
        atomicAdd(&hist[bin], 1u);
      }
    }
  __syncthreads();
  for (int i = tid; i < NBINS; i += NT) {
    unsigned h = hist[i];
    if (h) atomicAdd(&ghist[(size_t)bc * NBINS + i], h);  // no return -> no stall
  }
}

// ---------------- K3: threshold bin per (b,c) ----------------
__global__ __launch_bounds__(64) void thr_k(
    const unsigned* __restrict__ ghist, unsigned* __restrict__ thr) {
  __shared__ unsigned binsh[NBINS];
  __shared__ unsigned ps[64];
  const int bc = blockIdx.x;
  const int lane = threadIdx.x;
  unsigned sum = 0;
#pragma unroll
  for (int k = 0; k < NBINS / 64; ++k) {
    int b = lane * (NBINS / 64) + k;
    unsigned h = ghist[(size_t)bc * NBINS + b];
    binsh[b] = h;
    sum += h;
  }
  ps[lane] = sum;
  __syncthreads();
  if (lane == 0) {
    unsigned cum = 0;
    int T = 0;
    for (int l = 63; l >= 0; --l) {
      if (cum + ps[l] >= (unsigned)TOPK) {
        for (int b = l * (NBINS / 64) + (NBINS / 64) - 1; b >= l * (NBINS / 64); --b) {
          cum += binsh[b];
          if (cum >= (unsigned)TOPK) { T = b; break; }
        }
        break;
      }
      cum += ps[l];
    }
    thr[bc] = (unsigned)T + BIN_BASE;
  }
}

// ---------------- K4: collect candidates into per-slice segments ----------------
// LDS counter + LDS staging + coalesced segment write + non-atomic count store.
__global__ __launch_bounds__(256) void collect_k(
    const float* __restrict__ sw, const unsigned* __restrict__ thr,
    unsigned long long* __restrict__ cand, unsigned* __restrict__ cnt8, int A) {
  __shared__ unsigned s_pos;
  __shared__ unsigned long long s_keys[SEGCAP];
  const int bc = blockIdx.x / SLICES;
  const int sl = blockIdx.x % SLICES;
  const int tid = threadIdx.x;
  if (tid == 0) s_pos = 0u;
  __syncthreads();

  const unsigned thr_hi = thr[bc];
  const float* srow = sw + (size_t)bc * A;
  const int n4 = A >> 2;
  const int per4 = (n4 + SLICES - 1) / SLICES;
  const int s4 = sl * per4, e4 = min(n4, s4 + per4);
  const float4* srow4 = (const float4*)srow;
  for (int i = s4 + tid; i < e4; i += NT) {
    float4 v = srow4[i];
    float vs[4] = {v.x, v.y, v.z, v.w};
#pragma unroll
    for (int j = 0; j < 4; ++j) {
      float s = vs[j];
      if (s > 0.01f) {
        unsigned bits = __float_as_uint(s);
        if ((bits >> 16) >= thr_hi) {
          unsigned a = (unsigned)(i * 4 + j);
          unsigned p = atomicAdd(&s_pos, 1u);  // LDS atomic: fast
          if (p < SEGCAP)
            s_keys[p] = ((unsigned long long)bits << 32) | (unsigned)(~a);
        }
      }
    }
  }
  if (sl == 0)  // scalar tail (A%4 != 0)
    for (int a = (n4 << 2) + tid; a < A; a += NT) {
      float s = srow[a];
      if (s > 0.01f) {
        unsigned bits = __float_as_uint(s);
        if ((bits >> 16) >= thr_hi) {
          unsigned p = atomicAdd(&s_pos, 1u);
          if (p < SEGCAP)
            s_keys[p] = ((unsigned long long)bits << 32) | (unsigned)(~(unsigned)a);
        }
      }
    }
  __syncthreads();
  const unsigned cnt = s_pos < (unsigned)SEGCAP ? s_pos : (unsigned)SEGCAP;
  unsigned long long* cbase = cand + ((size_t)bc * SLICES + sl) * SEGCAP;
  for (unsigned i = tid; i < cnt; i += NT) cbase[i] = s_keys[i];  // coalesced
  if (tid == 0) cnt8[bc * SLICES + sl] = cnt;  // plain store, always written
}

// ---------------- K5: gather segments + sort + decode + NMS + write ----------------
__global__ __launch_bounds__(256) void nms_k(
    const unsigned long long* __restrict__ cand, const unsigned* __restrict__ cnt8,
    const float* __restrict__ loc, const float* __restrict__ anch,
    float* __restrict__ out, int B, int A) {
  __shared__ unsigned long long keys[CAP];
  __shared__ float bxv[TOPK][4];
  __shared__ float barea[TOPK];
  __shared__ float bscore[TOPK];
  __shared__ unsigned sup[TOPK][8];
  __shared__ unsigned keepm[8];
  __shared__ int s_segcnt[SLICES];
  __shared__ int s_segoff[SLICES + 1];

  const int tid = threadIdx.x;
  const int bc = blockIdx.x;       // b*21 + c
  const int b = bc / CNUM;
  const int c = bc - b * CNUM;
  float* obase = out + (size_t)bc * (TOPK * 5);
  if (c == 0) {
    for (int i = tid; i < TOPK * 5; i += NT) obase[i] = 0.f;
    return;
  }
  const int bc20 = b * CC + (c - 1);

  if (tid < SLICES) {
    unsigned v = cnt8[bc20 * SLICES + tid];
    s_segcnt[tid] = v < (unsigned)SEGCAP ? (int)v : SEGCAP;
  }
  __syncthreads();
  if (tid == 0) {
    int o = 0;
    for (int s2 = 0; s2 < SLICES; ++s2) { s_segoff[s2] = o; o += s_segcnt[s2]; }
    s_segoff[SLICES] = o;
  }
  __syncthreads();
  const int n_cand = s_segoff[SLICES];  // <= CAP

  int P2 = 256;
  while (P2 < n_cand) P2 <<= 1;

  const unsigned long long* cb = cand + (size_t)bc20 * SLICES * SEGCAP;
  for (int s2 = 0; s2 < SLICES; ++s2)
    for (int i = tid; i < s_segcnt[s2]; i += NT)
      keys[s_segoff[s2] + i] = cb[s2 * SEGCAP + i];
  for (int i = tid; i < P2; i += NT)
    if (i >= n_cand) keys[i] = 0ull;
  __syncthreads();

  for (int size = 2; size <= P2; size <<= 1) {
    for (int stride = size >> 1; stride > 0; stride >>= 1) {
      for (int i = tid; i < P2; i += NT) {
        int j = i ^ stride;
        if (j > i) {
          unsigned long long ki = keys[i], kj = keys[j];
          bool desc = ((i & size) == 0);
          if (desc ? (ki < kj) : (ki > kj)) { keys[i] = kj; keys[j] = ki; }
        }
      }
      __syncthreads();
    }
  }

  const int n = n_cand < TOPK ? n_cand : TOPK;

  if (tid < n) {
    unsigned long long k = keys[tid];
    float s = __uint_as_float((unsigned)(k >> 32));
    unsigned a = ~(unsigned)(k & 0xFFFFFFFFull);
    const float* lp = loc + ((size_t)b * A + a) * 4;
    const float* an = anch + (size_t)a * 4;
    float l0 = lp[0], l1 = lp[1], l2 = lp[2], l3 = lp[3];
    float acx = an[0], acy = an[1], aw = an[2], ah = an[3];
    float cx = __fadd_rn(acx, __fmul_rn(__fmul_rn(l0, 0.1f), aw));
    float cy = __fadd_rn(acy, __fmul_rn(__fmul_rn(l1, 0.1f), ah));
    float w  = __fmul_rn(aw, cr_expf(__fmul_rn(l2, 0.2f)));
    float h  = __fmul_rn(ah, cr_expf(__fmul_rn(l3, 0.2f)));
    float hw = __fmul_rn(w, 0.5f), hh = __fmul_rn(h, 0.5f);
    float x1 = __fsub_rn(cx, hw), y1 = __fsub_rn(cy, hh);
    float x2 = __fadd_rn(cx, hw), y2 = __fadd_rn(cy, hh);
    bxv[tid][0] = x1; bxv[tid][1] = y1; bxv[tid][2] = x2; bxv[tid][3] = y2;
    barea[tid] = __fmul_rn(fmaxf(__fsub_rn(x2, x1), 0.f),
                           fmaxf(__fsub_rn(y2, y1), 0.f));
    bscore[tid] = s;
  }
  for (int i = tid; i < TOPK * 8; i += NT) ((unsigned*)sup)[i] = 0u;
  __syncthreads();

  for (int idx = tid; idx < TOPK * TOPK; idx += NT) {
    int i = idx / TOPK;
    int j = idx - i * TOPK;
    if (j > i && j < n && i < n) {
      float ltx = fmaxf(bxv[i][0], bxv[j][0]);
      float lty = fmaxf(bxv[i][1], bxv[j][1]);
      float rbx = fminf(bxv[i][2], bxv[j][2]);
      float rby = fminf(bxv[i][3], bxv[j][3]);
      float iw = fmaxf(__fsub_rn(rbx, ltx), 0.f);
      float ih = fmaxf(__fsub_rn(rby, lty), 0.f);
      float inter = __fmul_rn(iw, ih);
      float denom = __fadd_rn(__fsub_rn(__fadd_rn(barea[i], barea[j]), inter), 1e-9f);
      float iou = __fdiv_rn(inter, denom);
      if (iou > 0.45f) atomicOr(&sup[i][j >> 5], 1u << (j & 31));
    }
  }
  __syncthreads();

  if (tid == 0) {
    unsigned km[8];
#pragma unroll
    for (int w = 0; w < 8; ++w) {
      int lo = w * 32;
      unsigned m2;
      if (n >= lo + 32) m2 = 0xFFFFFFFFu;
      else if (n <= lo) m2 = 0u;
      else m2 = (1u << (n - lo)) - 1u;
      km[w] = m2;
    }
    for (int i = 0; i < n; ++i) {
      if ((km[i >> 5] >> (i & 31)) & 1u) {
#pragma unroll
        for (int w = 0; w < 8; ++w) km[w] &= ~sup[i][w];
      }
    }
#pragma unroll
    for (int w = 0; w < 8; ++w) keepm[w] = km[w];
  }
  __syncthreads();

  if (tid < TOPK) {
    float s = 0.f, o0 = 0.f, o1 = 0.f, o2 = 0.f, o3 = 0.f;
    if (tid < n && ((keepm[tid >> 5] >> (tid & 31)) & 1u)) {
      s = bscore[tid];
      o0 = bxv[tid][0]; o1 = bxv[tid][1]; o2 = bxv[tid][2]; o3 = bxv[tid][3];
    }
    obase[tid * 5 + 0] = s;
    obase[tid * 5 + 1] = o0;
    obase[tid * 5 + 2] = o1;
    obase[tid * 5 + 3] = o2;
    obase[tid * 5 + 4] = o3;
  }
}

// ================= legacy fallback (R1 path, small workspace) =================
__global__ __launch_bounds__(256) void softmax_MS(
    const float* __restrict__ cls, float2* __restrict__ ms, int B, int A) {
  int i = blockIdx.x * 256 + threadIdx.x;
  if (i >= B * A) return;
  const float* row = cls + (size_t)i * CNUM;
  float x[CNUM];
#pragma unroll
  for (int c = 0; c < CNUM; ++c) x[c] = row[c];
  float m = x[0];
#pragma unroll
  for (int c = 1; c < CNUM; ++c) m = fmaxf(m, x[c]);
  float S = 0.f;
#pragma unroll
  for (int c = 0; c < CNUM; ++c) S = __fadd_rn(S, cr_expf(__fsub_rn(x[c], m)));
  ms[i] = make_float2(m, S);
}

__device__ __forceinline__ float score_direct(const float* __restrict__ cls,
                                              int b, int A, int a, int c) {
  const float* row = cls + ((size_t)b * A + a) * CNUM;
  float x[CNUM];
#pragma unroll
  for (int k = 0; k < CNUM; ++k) x[k] = row[k];
  float m = x[0];
#pragma unroll
  for (int k = 1; k < CNUM; ++k) m = fmaxf(m, x[k]);
  float S = 0.f, ec = 0.f;
#pragma unroll
  for (int k = 0; k < CNUM; ++k) {
    float e = cr_expf(__fsub_rn(x[k], m));
    S = __fadd_rn(S, e);
    if (k == c) ec = e;
  }
  return __fdiv_rn(ec, S);
}

template <int MODE>
__global__ __launch_bounds__(256) void topk_nms(
    const float* __restrict__ cls, const float* __restrict__ sw,
    const float* __restrict__ loc, const float* __restrict__ anch,
    float* __restrict__ out, int B, int A) {
  __shared__ unsigned hist[NBINS];
  __shared__ unsigned long long keys[CAP];
  __shared__ float bxv[TOPK][4];
  __shared__ float barea[TOPK];
  __shared__ float bscore[TOPK];
  __shared__ unsigned sup[TOPK][8];
  __shared__ unsigned keepm[8];
  __shared__ int s_cnt;
  __shared__ int s_T;

  const int tid = threadIdx.x;
  const int bc = blockIdx.x;
  const int b = bc / CNUM;
  const int c = bc - b * CNUM;
  float* obase = out + (size_t)bc * (TOPK * 5);
  if (c == 0) {
    for (int i = tid; i < TOPK * 5; i += NT) obase[i] = 0.f;
    return;
  }
  const float* srow =
      (MODE == 0) ? (sw + ((size_t)b * CC + (c - 1)) * A) : nullptr;
  const float2* msrow = (MODE == 2) ? ((const float2*)sw + (size_t)b * A) : nullptr;

  auto get_score = [&](int a) -> float {
    if (MODE == 0) return srow[a];
    if (MODE == 2) {
      float2 v = msrow[a];
      float xc = cls[((size_t)b * A + a) * CNUM + c];
      return __fdiv_rn(cr_expf(__fsub_rn(xc, v.x)), v.y);
    }
    return score_direct(cls, b, A, a, c);
  };

  for (int i = tid; i < NBINS; i += NT) hist[i] = 0;
  if (tid == 0) { s_cnt = 0; s_T = 0; }
  __syncthreads();

  for (int a = tid; a < A; a += NT) {
    float s = get_score(a);
    if (s > 0.01f) {
      unsigned bits = __float_as_uint(s);
      int bin = (int)(bits >> 16) - (int)BIN_BASE;
      bin = bin < (NBINS - 1) ? bin : (NBINS - 1);
      atomicAdd(&hist[bin], 1u);
    }
  }
  __syncthreads();

  if (tid == 0) {
    unsigned cum = 0;
    int T = 0;
    for (int i = NBINS - 1; i >= 0; --i) {
      cum += hist[i];
      if (cum >= TOPK) { T = i; break; }
    }
    s_T = T;
  }
  __syncthreads();
  const unsigned thr_hi = (unsigned)s_T + BIN_BASE;

  for (int a = tid; a < A; a += NT) {
    float s = get_score(a);
    if (s > 0.01f) {
      unsigned bits = __float_as_uint(s);
      if ((bits >> 16) >= thr_hi) {
        int pos = atomicAdd(&s_cnt, 1);
        if (pos < CAP)
          keys[pos] = ((unsigned long long)bits << 32) | (unsigned)(~(unsigned)a);
      }
    }
  }
  __syncthreads();
  int cnt = s_cnt < CAP ? s_cnt : CAP;
  for (int i = tid; i < CAP; i += NT)
    if (i >= cnt) keys[i] = 0ull;
  __syncthreads();

  for (int size = 2; size <= CAP; size <<= 1) {
    for (int stride = size >> 1; stride > 0; stride >>= 1) {
      for (int i = tid; i < CAP; i += NT) {
        int j = i ^ stride;
        if (j > i) {
          unsigned long long ki = keys[i], kj = keys[j];
          bool desc = ((i & size) == 0);
          if (desc ? (ki < kj) : (ki > kj)) { keys[i] = kj; keys[j] = ki; }
        }
      }
      __syncthreads();
    }
  }

  const int n = cnt < TOPK ? cnt : TOPK;

  if (tid < n) {
    unsigned long long k = keys[tid];
    float s = __uint_as_float((unsigned)(k >> 32));
    unsigned a = ~(unsigned)(k & 0xFFFFFFFFull);
    const float* lp = loc + ((size_t)b * A + a) * 4;
    const float* an = anch + (size_t)a * 4;
    float l0 = lp[0], l1 = lp[1], l2 = lp[2], l3 = lp[3];
    float acx = an[0], acy = an[1], aw = an[2], ah = an[3];
    float cx = __fadd_rn(acx, __fmul_rn(__fmul_rn(l0, 0.1f), aw));
    float cy = __fadd_rn(acy, __fmul_rn(__fmul_rn(l1, 0.1f), ah));
    float w  = __fmul_rn(aw, cr_expf(__fmul_rn(l2, 0.2f)));
    float h  = __fmul_rn(ah, cr_expf(__fmul_rn(l3, 0.2f)));
    float hw = __fmul_rn(w, 0.5f), hh = __fmul_rn(h, 0.5f);
    float x1 = __fsub_rn(cx, hw), y1 = __fsub_rn(cy, hh);
    float x2 = __fadd_rn(cx, hw), y2 = __fadd_rn(cy, hh);
    bxv[tid][0] = x1; bxv[tid][1] = y1; bxv[tid][2] = x2; bxv[tid][3] = y2;
    barea[tid] = __fmul_rn(fmaxf(__fsub_rn(x2, x1), 0.f),
                           fmaxf(__fsub_rn(y2, y1), 0.f));
    bscore[tid] = s;
  }
  for (int i = tid; i < TOPK * 8; i += NT) ((unsigned*)sup)[i] = 0u;
  __syncthreads();

  for (int idx = tid; idx < TOPK * TOPK; idx += NT) {
    int i = idx / TOPK;
    int j = idx - i * TOPK;
    if (j > i && j < n && i < n) {
      float ltx = fmaxf(bxv[i][0], bxv[j][0]);
      float lty = fmaxf(bxv[i][1], bxv[j][1]);
      float rbx = fminf(bxv[i][2], bxv[j][2]);
      float rby = fminf(bxv[i][3], bxv[j][3]);
      float iw = fmaxf(__fsub_rn(rbx, ltx), 0.f);
      float ih = fmaxf(__fsub_rn(rby, lty), 0.f);
      float inter = __fmul_rn(iw, ih);
      float denom = __fadd_rn(__fsub_rn(__fadd_rn(barea[i], barea[j]), inter), 1e-9f);
      float iou = __fdiv_rn(inter, denom);
      if (iou > 0.45f) atomicOr(&sup[i][j >> 5], 1u << (j & 31));
    }
  }
  __syncthreads();

  if (tid == 0) {
    unsigned km[8];
#pragma unroll
    for (int w = 0; w < 8; ++w) {
      int lo = w * 32;
      unsigned m2;
      if (n >= lo + 32) m2 = 0xFFFFFFFFu;
      else if (n <= lo) m2 = 0u;
      else m2 = (1u << (n - lo)) - 1u;
      km[w] = m2;
    }
    for (int i = 0; i < n; ++i) {
      if ((km[i >> 5] >> (i & 31)) & 1u) {
#pragma unroll
        for (int w = 0; w < 8; ++w) km[w] &= ~sup[i][w];
      }
    }
#pragma unroll
    for (int w = 0; w < 8; ++w) keepm[w] = km[w];
  }
  __syncthreads();

  if (tid < TOPK) {
    float s = 0.f, o0 = 0.f, o1 = 0.f, o2 = 0.f, o3 = 0.f;
    if (tid < n && ((keepm[tid >> 5] >> (tid & 31)) & 1u)) {
      s = bscore[tid];
      o0 = bxv[tid][0]; o1 = bxv[tid][1]; o2 = bxv[tid][2]; o3 = bxv[tid][3];
    }
    obase[tid * 5 + 0] = s;
    obase[tid * 5 + 1] = o0;
    obase[tid * 5 + 2] = o1;
    obase[tid * 5 + 3] = o2;
    obase[tid * 5 + 4] = o3;
  }
}

extern "C" void kernel_launch(void* const* d_in, const int* in_sizes, int n_in,
                              void* d_out, int out_size, void* d_ws, size_t ws_size,
                              hipStream_t stream) {
  const float* cls  = (const float*)d_in[0];
  const float* loc  = (const float*)d_in[1];
  const float* anch = (const float*)d_in[2];
  float* out = (float*)d_out;

  const int A = in_sizes[2] / 4;
  const int B = in_sizes[1] / (4 * A);
  const long long BA = (long long)B * A;
  const int NBC = B * CC;  // 640 foreground (b,c) pairs

  // workspace layout (256-aligned pieces)
  auto al = [](size_t x) { return (x + 255) & ~(size_t)255; };
  const size_t sz_sw   = al((size_t)NBC * A * sizeof(float));
  const size_t sz_cand = al((size_t)NBC * SLICES * SEGCAP * sizeof(unsigned long long));
  const size_t sz_hist = al((size_t)NBC * NBINS * sizeof(unsigned));
  const size_t sz_cnt  = al((size_t)NBC * SLICES * sizeof(unsigned));
  const size_t sz_thr  = al((size_t)NBC * sizeof(unsigned));
  const size_t need_new = sz_sw + sz_cand + sz_hist + sz_cnt + sz_thr;

  if (ws_size >= need_new) {
    char* w = (char*)d_ws;
    float* sw = (float*)w;
    unsigned long long* cand = (unsigned long long*)(w + sz_sw);
    unsigned* ghist = (unsigned*)(w + sz_sw + sz_cand);
    unsigned* cnt8 = (unsigned*)(w + sz_sw + sz_cand + sz_hist);
    unsigned* thr = (unsigned*)(w + sz_sw + sz_cand + sz_hist + sz_cnt);

    // zero hist (cnt8 is fully overwritten by collect_k, no zeroing needed)
    hipMemsetAsync(ghist, 0, sz_hist, stream);

    const int k1_grid = (int)((BA / 4 + 255) / 256) + 1;
    softmax_T4<<<k1_grid, 256, 0, stream>>>(cls, sw, B, A);
    hist_k<<<NBC * SLICES, NT, 0, stream>>>(sw, ghist, A);
    thr_k<<<NBC, 64, 0, stream>>>(ghist, thr);
    collect_k<<<NBC * SLICES, NT, 0, stream>>>(sw, thr, cand, cnt8, A);
    nms_k<<<B * CNUM, NT, 0, stream>>>(cand, cnt8, loc, anch, out, B, A);
    return;
  }

  // legacy fallbacks
  const size_t need_full = (size_t)NBC * A * sizeof(float);
  const size_t need_ms   = (size_t)BA * sizeof(float2);
  const int tot = (int)BA;
  if (ws_size >= need_full) {
    float* sw = (float*)d_ws;
    const int k1_grid = (int)((BA / 4 + 255) / 256) + 1;
    softmax_T4<<<k1_grid, 256, 0, stream>>>(cls, sw, B, A);
    topk_nms<0><<<B * CNUM, NT, 0, stream>>>(cls, sw, loc, anch, out, B, A);
  } else if (ws_size >= need_ms) {
    float2* ms = (float2*)d_ws;
    softmax_MS<<<(tot + 255) / 256, 256, 0, stream>>>(cls, ms, B, A);
    topk_nms<2><<<B * CNUM, NT, 0, stream>>>(cls, (const float*)ms, loc, anch, out, B, A);
  } else {
    topk_nms<1><<<B * CNUM, NT, 0, stream>>>(cls, nullptr, loc, anch, out, B, A);
  }
}

// Round 14
// 217.248 us; speedup vs baseline: 1.5437x; 1.0709x over previous
//
#include <hip/hip_runtime.h>
#include <math.h>

// SSD Detect post-processing (R10):
//   K1 softmax_T4 : softmax + transpose to [B,20,A], 4 anchors/thread, float4 IO
//   K2 hist_k     : per-(b,c) score histogram, 8 slice-blocks each, LDS + atomics
//   K3 thr_k      : exact top-200 threshold bin per (b,c)
//   K4 collect_k  : compact candidates into per-slice segments via LDS counter
//   K5 nms_k      : sort + decode-to-registers + FUSED IoU/greedy-NMS loop
//                   (R9 profile: sup-matrix IoU ~1.6MB LDS/block + serial
//                    resolve chain ~12us dominated the 74us; fused loop deletes
//                    both — one broadcast read + inline IoU per iteration)
// Numerics mirror the reference f32 op sequence (explicit __f*_rn, f64 exp).

constexpr int CNUM  = 21;
constexpr int CC    = 20;      // foreground classes
constexpr int TOPK  = 200;
constexpr int NT    = 256;
constexpr int NBINS = 1024;
constexpr int SLICES = 8;
constexpr int SEGCAP = 256;            // per-slice candidate capacity
constexpr int CAP   = SLICES * SEGCAP; // 2048, sort buffer size
constexpr unsigned BIN_BASE = 0x3C23u;  // bits(0.01f)>>16

__device__ __forceinline__ float cr_expf(float x) {
  return (float)exp((double)x);  // ~correctly-rounded f32 exp
}

// ---------------- K1: softmax + transpose, 4 rows/thread ----------------
__global__ __launch_bounds__(256) void softmax_T4(
    const float* __restrict__ cls, float* __restrict__ sw, int B, int A) {
  const long long r0 = ((long long)blockIdx.x * 256 + threadIdx.x) * 4;
  const long long BA = (long long)B * A;
  if (r0 >= BA) return;

  if (r0 + 3 < BA && (A & 3) == 0) {
    // 4 rows, same image (A%4==0 and r0%4==0 => no image straddle)
    const int b = (int)(r0 / A);
    const int a0 = (int)(r0 - (long long)b * A);
    float xf[84];
    const float4* p = (const float4*)(cls + r0 * CNUM);
#pragma unroll
    for (int k = 0; k < 21; ++k) {  // 84 floats = 21 aligned float4
      float4 q = p[k];
      xf[4 * k + 0] = q.x; xf[4 * k + 1] = q.y;
      xf[4 * k + 2] = q.z; xf[4 * k + 3] = q.w;
    }
    float S[4];
#pragma unroll
    for (int r = 0; r < 4; ++r) {
      const int base = 21 * r;
      float m = xf[base];
#pragma unroll
      for (int c = 1; c < CNUM; ++c) m = fmaxf(m, xf[base + c]);
      float s = 0.f;
#pragma unroll
      for (int c = 0; c < CNUM; ++c) {
        float e = cr_expf(__fsub_rn(xf[base + c], m));
        xf[base + c] = e;  // overwrite x with e
        s = __fadd_rn(s, e);
      }
      S[r] = s;
    }
#pragma unroll
    for (int c = 1; c < CNUM; ++c) {
      float4 w;
      w.x = __fdiv_rn(xf[0 * 21 + c], S[0]);
      w.y = __fdiv_rn(xf[1 * 21 + c], S[1]);
      w.z = __fdiv_rn(xf[2 * 21 + c], S[2]);
      w.w = __fdiv_rn(xf[3 * 21 + c], S[3]);
      *(float4*)(sw + ((size_t)b * CC + (c - 1)) * A + a0) = w;
    }
  } else {
    // generic scalar tail
    for (long long r = r0; r < BA && r < r0 + 4; ++r) {
      const int b = (int)(r / A);
      const int a = (int)(r - (long long)b * A);
      const float* row = cls + r * CNUM;
      float x[CNUM];
#pragma unroll
      for (int c = 0; c < CNUM; ++c) x[c] = row[c];
      float m = x[0];
#pragma unroll
      for (int c = 1; c < CNUM; ++c) m = fmaxf(m, x[c]);
      float e[CNUM], s = 0.f;
#pragma unroll
      for (int c = 0; c < CNUM; ++c) {
        e[c] = cr_expf(__fsub_rn(x[c], m));
        s = __fadd_rn(s, e[c]);
      }
#pragma unroll
      for (int c = 1; c < CNUM; ++c)
        sw[((size_t)b * CC + (c - 1)) * A + a] = __fdiv_rn(e[c], s);
    }
  }
}

// ---------------- K2: sliced histogram ----------------
__global__ __launch_bounds__(256) void hist_k(
    const float* __restrict__ sw, unsigned* __restrict__ ghist, int A) {
  __shared__ unsigned hist[NBINS];
  const int bc = blockIdx.x / SLICES;
  const int sl = blockIdx.x % SLICES;
  const int tid = threadIdx.x;
  for (int i = tid; i < NBINS; i += NT) hist[i] = 0;
  __syncthreads();

  const float* srow = sw + (size_t)bc * A;
  const int n4 = A >> 2;
  const int per4 = (n4 + SLICES - 1) / SLICES;
  const int s4 = sl * per4, e4 = min(n4, s4 + per4);
  const float4* srow4 = (const float4*)srow;
  for (int i = s4 + tid; i < e4; i += NT) {
    float4 v = srow4[i];
    float vs[4] = {v.x, v.y, v.z, v.w};
#pragma unroll
    for (int j = 0; j < 4; ++j) {
      float s = vs[j];
      if (s > 0.01f) {
        unsigned bits = __float_as_uint(s);
        int bin = (int)(bits >> 16) - (int)BIN_BASE;
        bin = bin < (NBINS - 1) ? bin : (NBINS - 1);
        atomicAdd(&hist[bin], 1u);
      }
    }
  }
  // scalar tail (A%4): only slice 0 handles it
  if (sl == 0)
    for (int a = (n4 << 2) + tid; a < A; a += NT) {
      float s = srow[a];
      if (s > 0.01f) {
        unsigned bits = __float_as_uint(s);
        int bin = (int)(bits >> 16) - (int)BIN_BASE;
        bin = bin < (NBINS - 1) ? bin : (NBINS - 1);
        atomicAdd(&hist[bin], 1u);
      }
    }
  __syncthreads();
  for (int i = tid; i < NBINS; i += NT) {
    unsigned h = hist[i];
    if (h) atomicAdd(&ghist[(size_t)bc * NBINS + i], h);  // no return -> no stall
  }
}

// ---------------- K3: threshold bin per (b,c) ----------------
__global__ __launch_bounds__(64) void thr_k(
    const unsigned* __restrict__ ghist, unsigned* __restrict__ thr) {
  __shared__ unsigned binsh[NBINS];
  __shared__ unsigned ps[64];
  const int bc = blockIdx.x;
  const int lane = threadIdx.x;
  unsigned sum = 0;
#pragma unroll
  for (int k = 0; k < NBINS / 64; ++k) {
    int b = lane * (NBINS / 64) + k;
    unsigned h = ghist[(size_t)bc * NBINS + b];
    binsh[b] = h;
    sum += h;
  }
  ps[lane] = sum;
  __syncthreads();
  if (lane == 0) {
    unsigned cum = 0;
    int T = 0;
    for (int l = 63; l >= 0; --l) {
      if (cum + ps[l] >= (unsigned)TOPK) {
        for (int b = l * (NBINS / 64) + (NBINS / 64) - 1; b >= l * (NBINS / 64); --b) {
          cum += binsh[b];
          if (cum >= (unsigned)TOPK) { T = b; break; }
        }
        break;
      }
      cum += ps[l];
    }
    thr[bc] = (unsigned)T + BIN_BASE;
  }
}

// ---------------- K4: collect candidates into per-slice segments ----------------
__global__ __launch_bounds__(256) void collect_k(
    const float* __restrict__ sw, const unsigned* __restrict__ thr,
    unsigned long long* __restrict__ cand, unsigned* __restrict__ cnt8, int A) {
  __shared__ unsigned s_pos;
  __shared__ unsigned long long s_keys[SEGCAP];
  const int bc = blockIdx.x / SLICES;
  const int sl = blockIdx.x % SLICES;
  const int tid = threadIdx.x;
  if (tid == 0) s_pos = 0u;
  __syncthreads();

  const unsigned thr_hi = thr[bc];
  const float* srow = sw + (size_t)bc * A;
  const int n4 = A >> 2;
  const int per4 = (n4 + SLICES - 1) / SLICES;
  const int s4 = sl * per4, e4 = min(n4, s4 + per4);
  const float4* srow4 = (const float4*)srow;
  for (int i = s4 + tid; i < e4; i += NT) {
    float4 v = srow4[i];
    float vs[4] = {v.x, v.y, v.z, v.w};
#pragma unroll
    for (int j = 0; j < 4; ++j) {
      float s = vs[j];
      if (s > 0.01f) {
        unsigned bits = __float_as_uint(s);
        if ((bits >> 16) >= thr_hi) {
          unsigned a = (unsigned)(i * 4 + j);
          unsigned p = atomicAdd(&s_pos, 1u);  // LDS atomic: fast
          if (p < SEGCAP)
            s_keys[p] = ((unsigned long long)bits << 32) | (unsigned)(~a);
        }
      }
    }
  }
  if (sl == 0)  // scalar tail (A%4 != 0)
    for (int a = (n4 << 2) + tid; a < A; a += NT) {
      float s = srow[a];
      if (s > 0.01f) {
        unsigned bits = __float_as_uint(s);
        if ((bits >> 16) >= thr_hi) {
          unsigned p = atomicAdd(&s_pos, 1u);
          if (p < SEGCAP)
            s_keys[p] = ((unsigned long long)bits << 32) | (unsigned)(~(unsigned)a);
        }
      }
    }
  __syncthreads();
  const unsigned cnt = s_pos < (unsigned)SEGCAP ? s_pos : (unsigned)SEGCAP;
  unsigned long long* cbase = cand + ((size_t)bc * SLICES + sl) * SEGCAP;
  for (unsigned i = tid; i < cnt; i += NT) cbase[i] = s_keys[i];  // coalesced
  if (tid == 0) cnt8[bc * SLICES + sl] = cnt;  // plain store, always written
}

// ---------------- K5: gather + sort + decode-to-regs + fused IoU/NMS + write ----------------
__global__ __launch_bounds__(256) void nms_k(
    const unsigned long long* __restrict__ cand, const unsigned* __restrict__ cnt8,
    const float* __restrict__ loc, const float* __restrict__ anch,
    float* __restrict__ out, int B, int A) {
  __shared__ unsigned long long keys[CAP];
  __shared__ float4 bxv[TOPK];     // (x1,y1,x2,y2)
  __shared__ float barea[TOPK];
  __shared__ unsigned keep[TOPK];
  __shared__ int s_segcnt[SLICES];
  __shared__ int s_segoff[SLICES + 1];

  const int tid = threadIdx.x;
  const int bc = blockIdx.x;       // b*21 + c
  const int b = bc / CNUM;
  const int c = bc - b * CNUM;
  float* obase = out + (size_t)bc * (TOPK * 5);
  if (c == 0) {  // background class: all zeros
    for (int i = tid; i < TOPK * 5; i += NT) obase[i] = 0.f;
    return;
  }
  const int bc20 = b * CC + (c - 1);

  if (tid < SLICES) {
    unsigned v = cnt8[bc20 * SLICES + tid];
    s_segcnt[tid] = v < (unsigned)SEGCAP ? (int)v : SEGCAP;
  }
  __syncthreads();
  if (tid == 0) {
    int o = 0;
    for (int s2 = 0; s2 < SLICES; ++s2) { s_segoff[s2] = o; o += s_segcnt[s2]; }
    s_segoff[SLICES] = o;
  }
  __syncthreads();
  const int n_cand = s_segoff[SLICES];  // <= CAP

  int P2 = 256;
  while (P2 < n_cand) P2 <<= 1;

  const unsigned long long* cb = cand + (size_t)bc20 * SLICES * SEGCAP;
  for (int s2 = 0; s2 < SLICES; ++s2)
    for (int i = tid; i < s_segcnt[s2]; i += NT)
      keys[s_segoff[s2] + i] = cb[s2 * SEGCAP + i];
  for (int i = tid; i < P2; i += NT)
    if (i >= n_cand) keys[i] = 0ull;
  __syncthreads();

  // bitonic sort, descending (key = score_bits:~index -> score desc, index asc)
  for (int size = 2; size <= P2; size <<= 1) {
    for (int stride = size >> 1; stride > 0; stride >>= 1) {
      for (int i = tid; i < P2; i += NT) {
        int j = i ^ stride;
        if (j > i) {
          unsigned long long ki = keys[i], kj = keys[j];
          bool desc = ((i & size) == 0);
          if (desc ? (ki < kj) : (ki > kj)) { keys[i] = kj; keys[j] = ki; }
        }
      }
      __syncthreads();
    }
  }

  const int n = n_cand < TOPK ? n_cand : TOPK;

  // decode my box into registers + publish to LDS for row-broadcast
  float mx1 = 0.f, my1 = 0.f, mx2 = 0.f, my2 = 0.f, marea = 0.f, mscore = 0.f;
  if (tid < TOPK) keep[tid] = (tid < n) ? 1u : 0u;
  if (tid < n) {
    unsigned long long k = keys[tid];
    mscore = __uint_as_float((unsigned)(k >> 32));
    unsigned a = ~(unsigned)(k & 0xFFFFFFFFull);
    const float* lp = loc + ((size_t)b * A + a) * 4;
    const float* an = anch + (size_t)a * 4;
    float l0 = lp[0], l1 = lp[1], l2 = lp[2], l3 = lp[3];
    float acx = an[0], acy = an[1], aw = an[2], ah = an[3];
    float cx = __fadd_rn(acx, __fmul_rn(__fmul_rn(l0, 0.1f), aw));
    float cy = __fadd_rn(acy, __fmul_rn(__fmul_rn(l1, 0.1f), ah));
    float w  = __fmul_rn(aw, cr_expf(__fmul_rn(l2, 0.2f)));
    float h  = __fmul_rn(ah, cr_expf(__fmul_rn(l3, 0.2f)));
    float hw = __fmul_rn(w, 0.5f), hh = __fmul_rn(h, 0.5f);
    mx1 = __fsub_rn(cx, hw); my1 = __fsub_rn(cy, hh);
    mx2 = __fadd_rn(cx, hw); my2 = __fadd_rn(cy, hh);
    marea = __fmul_rn(fmaxf(__fsub_rn(mx2, mx1), 0.f),
                      fmaxf(__fsub_rn(my2, my1), 0.f));
    bxv[tid] = make_float4(mx1, my1, mx2, my2);
    barea[tid] = marea;
  }
  __syncthreads();

  // fused greedy NMS: iterate pivots; each thread owns column tid.
  // Reads: keep[i], bxv[i], barea[i] (broadcast). Writes: keep[tid] only.
  // Barrier at loop end publishes iteration i's writes before i+1's read.
  unsigned my_keep = (tid < n) ? 1u : 0u;
  for (int i = 0; i < n; ++i) {
    unsigned ki = keep[i];
    float4 bi = bxv[i];
    float ia = barea[i];
    if (ki && my_keep && tid > i && tid < n) {
      float ltx = fmaxf(bi.x, mx1);
      float lty = fmaxf(bi.y, my1);
      float rbx = fminf(bi.z, mx2);
      float rby = fminf(bi.w, my2);
      float iw = fmaxf(__fsub_rn(rbx, ltx), 0.f);
      float ih = fmaxf(__fsub_rn(rby, lty), 0.f);
      float inter = __fmul_rn(iw, ih);
      float denom = __fadd_rn(__fsub_rn(__fadd_rn(ia, marea), inter), 1e-9f);
      float iou = __fdiv_rn(inter, denom);
      if (iou > 0.45f) { my_keep = 0u; keep[tid] = 0u; }
    }
    __syncthreads();
  }

  // write 200 rows of (score, x1, y1, x2, y2)
  if (tid < TOPK) {
    float s = 0.f, o0 = 0.f, o1 = 0.f, o2 = 0.f, o3 = 0.f;
    if (tid < n && my_keep) {
      s = mscore; o0 = mx1; o1 = my1; o2 = mx2; o3 = my2;
    }
    obase[tid * 5 + 0] = s;
    obase[tid * 5 + 1] = o0;
    obase[tid * 5 + 2] = o1;
    obase[tid * 5 + 3] = o2;
    obase[tid * 5 + 4] = o3;
  }
}

// ================= legacy fallback (R1 path, small workspace) =================
__global__ __launch_bounds__(256) void softmax_MS(
    const float* __restrict__ cls, float2* __restrict__ ms, int B, int A) {
  int i = blockIdx.x * 256 + threadIdx.x;
  if (i >= B * A) return;
  const float* row = cls + (size_t)i * CNUM;
  float x[CNUM];
#pragma unroll
  for (int c = 0; c < CNUM; ++c) x[c] = row[c];
  float m = x[0];
#pragma unroll
  for (int c = 1; c < CNUM; ++c) m = fmaxf(m, x[c]);
  float S = 0.f;
#pragma unroll
  for (int c = 0; c < CNUM; ++c) S = __fadd_rn(S, cr_expf(__fsub_rn(x[c], m)));
  ms[i] = make_float2(m, S);
}

__device__ __forceinline__ float score_direct(const float* __restrict__ cls,
                                              int b, int A, int a, int c) {
  const float* row = cls + ((size_t)b * A + a) * CNUM;
  float x[CNUM];
#pragma unroll
  for (int k = 0; k < CNUM; ++k) x[k] = row[k];
  float m = x[0];
#pragma unroll
  for (int k = 1; k < CNUM; ++k) m = fmaxf(m, x[k]);
  float S = 0.f, ec = 0.f;
#pragma unroll
  for (int k = 0; k < CNUM; ++k) {
    float e = cr_expf(__fsub_rn(x[k], m));
    S = __fadd_rn(S, e);
    if (k == c) ec = e;
  }
  return __fdiv_rn(ec, S);
}

template <int MODE>
__global__ __launch_bounds__(256) void topk_nms(
    const float* __restrict__ cls, const float* __restrict__ sw,
    const float* __restrict__ loc, const float* __restrict__ anch,
    float* __restrict__ out, int B, int A) {
  __shared__ unsigned hist[NBINS];
  __shared__ unsigned long long keys[CAP];
  __shared__ float bxv[TOPK][4];
  __shared__ float barea[TOPK];
  __shared__ float bscore[TOPK];
  __shared__ unsigned sup[TOPK][8];
  __shared__ unsigned keepm[8];
  __shared__ int s_cnt;
  __shared__ int s_T;

  const int tid = threadIdx.x;
  const int bc = blockIdx.x;
  const int b = bc / CNUM;
  const int c = bc - b * CNUM;
  float* obase = out + (size_t)bc * (TOPK * 5);
  if (c == 0) {
    for (int i = tid; i < TOPK * 5; i += NT) obase[i] = 0.f;
    return;
  }
  const float* srow =
      (MODE == 0) ? (sw + ((size_t)b * CC + (c - 1)) * A) : nullptr;
  const float2* msrow = (MODE == 2) ? ((const float2*)sw + (size_t)b * A) : nullptr;

  auto get_score = [&](int a) -> float {
    if (MODE == 0) return srow[a];
    if (MODE == 2) {
      float2 v = msrow[a];
      float xc = cls[((size_t)b * A + a) * CNUM + c];
      return __fdiv_rn(cr_expf(__fsub_rn(xc, v.x)), v.y);
    }
    return score_direct(cls, b, A, a, c);
  };

  for (int i = tid; i < NBINS; i += NT) hist[i] = 0;
  if (tid == 0) { s_cnt = 0; s_T = 0; }
  __syncthreads();

  for (int a = tid; a < A; a += NT) {
    float s = get_score(a);
    if (s > 0.01f) {
      unsigned bits = __float_as_uint(s);
      int bin = (int)(bits >> 16) - (int)BIN_BASE;
      bin = bin < (NBINS - 1) ? bin : (NBINS - 1);
      atomicAdd(&hist[bin], 1u);
    }
  }
  __syncthreads();

  if (tid == 0) {
    unsigned cum = 0;
    int T = 0;
    for (int i = NBINS - 1; i >= 0; --i) {
      cum += hist[i];
      if (cum >= TOPK) { T = i; break; }
    }
    s_T = T;
  }
  __syncthreads();
  const unsigned thr_hi = (unsigned)s_T + BIN_BASE;

  for (int a = tid; a < A; a += NT) {
    float s = get_score(a);
    if (s > 0.01f) {
      unsigned bits = __float_as_uint(s);
      if ((bits >> 16) >= thr_hi) {
        int pos = atomicAdd(&s_cnt, 1);
        if (pos < CAP)
          keys[pos] = ((unsigned long long)bits << 32) | (unsigned)(~(unsigned)a);
      }
    }
  }
  __syncthreads();
  int cnt = s_cnt < CAP ? s_cnt : CAP;
  for (int i = tid; i < CAP; i += NT)
    if (i >= cnt) keys[i] = 0ull;
  __syncthreads();

  for (int size = 2; size <= CAP; size <<= 1) {
    for (int stride = size >> 1; stride > 0; stride >>= 1) {
      for (int i = tid; i < CAP; i += NT) {
        int j = i ^ stride;
        if (j > i) {
          unsigned long long ki = keys[i], kj = keys[j];
          bool desc = ((i & size) == 0);
          if (desc ? (ki < kj) : (ki > kj)) { keys[i] = kj; keys[j] = ki; }
        }
      }
      __syncthreads();
    }
  }

  const int n = cnt < TOPK ? cnt : TOPK;

  if (tid < n) {
    unsigned long long k = keys[tid];
    float s = __uint_as_float((unsigned)(k >> 32));
    unsigned a = ~(unsigned)(k & 0xFFFFFFFFull);
    const float* lp = loc + ((size_t)b * A + a) * 4;
    const float* an = anch + (size_t)a * 4;
    float l0 = lp[0], l1 = lp[1], l2 = lp[2], l3 = lp[3];
    float acx = an[0], acy = an[1], aw = an[2], ah = an[3];
    float cx = __fadd_rn(acx, __fmul_rn(__fmul_rn(l0, 0.1f), aw));
    float cy = __fadd_rn(acy, __fmul_rn(__fmul_rn(l1, 0.1f), ah));
    float w  = __fmul_rn(aw, cr_expf(__fmul_rn(l2, 0.2f)));
    float h  = __fmul_rn(ah, cr_expf(__fmul_rn(l3, 0.2f)));
    float hw = __fmul_rn(w, 0.5f), hh = __fmul_rn(h, 0.5f);
    float x1 = __fsub_rn(cx, hw), y1 = __fsub_rn(cy, hh);
    float x2 = __fadd_rn(cx, hw), y2 = __fadd_rn(cy, hh);
    bxv[tid][0] = x1; bxv[tid][1] = y1; bxv[tid][2] = x2; bxv[tid][3] = y2;
    barea[tid] = __fmul_rn(fmaxf(__fsub_rn(x2, x1), 0.f),
                           fmaxf(__fsub_rn(y2, y1), 0.f));
    bscore[tid] = s;
  }
  for (int i = tid; i < TOPK * 8; i += NT) ((unsigned*)sup)[i] = 0u;
  __syncthreads();

  for (int idx = tid; idx < TOPK * TOPK; idx += NT) {
    int i = idx / TOPK;
    int j = idx - i * TOPK;
    if (j > i && j < n && i < n) {
      float ltx = fmaxf(bxv[i][0], bxv[j][0]);
      float lty = fmaxf(bxv[i][1], bxv[j][1]);
      float rbx = fminf(bxv[i][2], bxv[j][2]);
      float rby = fminf(bxv[i][3], bxv[j][3]);
      float iw = fmaxf(__fsub_rn(rbx, ltx), 0.f);
      float ih = fmaxf(__fsub_rn(rby, lty), 0.f);
      float inter = __fmul_rn(iw, ih);
      float denom = __fadd_rn(__fsub_rn(__fadd_rn(barea[i], barea[j]), inter), 1e-9f);
      float iou = __fdiv_rn(inter, denom);
      if (iou > 0.45f) atomicOr(&sup[i][j >> 5], 1u << (j & 31));
    }
  }
  __syncthreads();

  if (tid == 0) {
    unsigned km[8];
#pragma unroll
    for (int w = 0; w < 8; ++w) {
      int lo = w * 32;
      unsigned m2;
      if (n >= lo + 32) m2 = 0xFFFFFFFFu;
      else if (n <= lo) m2 = 0u;
      else m2 = (1u << (n - lo)) - 1u;
      km[w] = m2;
    }
    for (int i = 0; i < n; ++i) {
      if ((km[i >> 5] >> (i & 31)) & 1u) {
#pragma unroll
        for (int w = 0; w < 8; ++w) km[w] &= ~sup[i][w];
      }
    }
#pragma unroll
    for (int w = 0; w < 8; ++w) keepm[w] = km[w];
  }
  __syncthreads();

  if (tid < TOPK) {
    float s = 0.f, o0 = 0.f, o1 = 0.f, o2 = 0.f, o3 = 0.f;
    if (tid < n && ((keepm[tid >> 5] >> (tid & 31)) & 1u)) {
      s = bscore[tid];
      o0 = bxv[tid][0]; o1 = bxv[tid][1]; o2 = bxv[tid][2]; o3 = bxv[tid][3];
    }
    obase[tid * 5 + 0] = s;
    obase[tid * 5 + 1] = o0;
    obase[tid * 5 + 2] = o1;
    obase[tid * 5 + 3] = o2;
    obase[tid * 5 + 4] = o3;
  }
}

extern "C" void kernel_launch(void* const* d_in, const int* in_sizes, int n_in,
                              void* d_out, int out_size, void* d_ws, size_t ws_size,
                              hipStream_t stream) {
  const float* cls  = (const float*)d_in[0];
  const float* loc  = (const float*)d_in[1];
  const float* anch = (const float*)d_in[2];
  float* out = (float*)d_out;

  const int A = in_sizes[2] / 4;
  const int B = in_sizes[1] / (4 * A);
  const long long BA = (long long)B * A;
  const int NBC = B * CC;  // 640 foreground (b,c) pairs

  // workspace layout (256-aligned pieces)
  auto al = [](size_t x) { return (x + 255) & ~(size_t)255; };
  const size_t sz_sw   = al((size_t)NBC * A * sizeof(float));
  const size_t sz_cand = al((size_t)NBC * SLICES * SEGCAP * sizeof(unsigned long long));
  const size_t sz_hist = al((size_t)NBC * NBINS * sizeof(unsigned));
  const size_t sz_cnt  = al((size_t)NBC * SLICES * sizeof(unsigned));
  const size_t sz_thr  = al((size_t)NBC * sizeof(unsigned));
  const size_t need_new = sz_sw + sz_cand + sz_hist + sz_cnt + sz_thr;

  if (ws_size >= need_new) {
    char* w = (char*)d_ws;
    float* sw = (float*)w;
    unsigned long long* cand = (unsigned long long*)(w + sz_sw);
    unsigned* ghist = (unsigned*)(w + sz_sw + sz_cand);
    unsigned* cnt8 = (unsigned*)(w + sz_sw + sz_cand + sz_hist);
    unsigned* thr = (unsigned*)(w + sz_sw + sz_cand + sz_hist + sz_cnt);

    // zero hist (cnt8 is fully overwritten by collect_k, no zeroing needed)
    hipMemsetAsync(ghist, 0, sz_hist, stream);

    const int k1_grid = (int)((BA / 4 + 255) / 256) + 1;
    softmax_T4<<<k1_grid, 256, 0, stream>>>(cls, sw, B, A);
    hist_k<<<NBC * SLICES, NT, 0, stream>>>(sw, ghist, A);
    thr_k<<<NBC, 64, 0, stream>>>(ghist, thr);
    collect_k<<<NBC * SLICES, NT, 0, stream>>>(sw, thr, cand, cnt8, A);
    nms_k<<<B * CNUM, NT, 0, stream>>>(cand, cnt8, loc, anch, out, B, A);
    return;
  }

  // legacy fallbacks
  const size_t need_full = (size_t)NBC * A * sizeof(float);
  const size_t need_ms   = (size_t)BA * sizeof(float2);
  const int tot = (int)BA;
  if (ws_size >= need_full) {
    float* sw = (float*)d_ws;
    const int k1_grid = (int)((BA / 4 + 255) / 256) + 1;
    softmax_T4<<<k1_grid, 256, 0, stream>>>(cls, sw, B, A);
    topk_nms<0><<<B * CNUM, NT, 0, stream>>>(cls, sw, loc, anch, out, B, A);
  } else if (ws_size >= need_ms) {
    float2* ms = (float2*)d_ws;
    softmax_MS<<<(tot + 255) / 256, 256, 0, stream>>>(cls, ms, B, A);
    topk_nms<2><<<B * CNUM, NT, 0, stream>>>(cls, (const float*)ms, loc, anch, out, B, A);
  } else {
    topk_nms<1><<<B * CNUM, NT, 0, stream>>>(cls, nullptr, loc, anch, out, B, A);
  }
}